// Round 7
// baseline (283.628 us; speedup 1.0000x reference)
//
#include <hip/hip_runtime.h>

// Problem constants: B=32, CIN=64, COUT=64, H=W=128, 1x1 conv
#define CIN   64
#define COUT  64
#define HW    16384           // 128*128
#define NPIX  (32 * HW)       // 524288
#define HALF  (NPIX / 2)      // 262144

// ---------------------------------------------------------------------------
// Prep: pack (w - wzp) into int8 dwords + fold requant params.
// wp[o*16 + k] = w[o][4k..4k+3]-wzp as 4 signed bytes (c0 in low byte).
// params[o] = { scale, bias/os + ozp, 0, as_float((128-izp)*sum_w) }
// ---------------------------------------------------------------------------
__global__ void prep_kernel(const int* __restrict__ w,
                            const float* __restrict__ wscale,
                            const int* __restrict__ wzp,
                            const float* __restrict__ bias,
                            const float* __restrict__ is_p,
                            const int* __restrict__ izp_p,
                            const float* __restrict__ os_p,
                            const int* __restrict__ ozp_p,
                            int* __restrict__ wp,
                            float4* __restrict__ params) {
    int o = threadIdx.x;
    if (o >= COUT) return;
    int zp = wzp[o];
    int sum = 0;
    #pragma unroll
    for (int k = 0; k < 16; ++k) {
        int c0 = w[o * CIN + 4 * k + 0] - zp;
        int c1 = w[o * CIN + 4 * k + 1] - zp;
        int c2 = w[o * CIN + 4 * k + 2] - zp;
        int c3 = w[o * CIN + 4 * k + 3] - zp;
        sum += c0 + c1 + c2 + c3;
        wp[o * 16 + k] = (c0 & 0xff) | ((c1 & 0xff) << 8) |
                         ((c2 & 0xff) << 16) | ((c3 & 0xff) << 24);
    }
    float4 pr;
    pr.x = is_p[0] * wscale[o] / os_p[0];
    pr.y = bias[o] / os_p[0] + (float)ozp_p[0];
    pr.z = 0.0f;
    pr.w = __int_as_float((128 - izp_p[0]) * sum);  // exact izp correction
    params[o] = pr;
}

__device__ __forceinline__ int pack4(int v0, int v1, int v2, int v3) {
    // x in [0,255]; (x-128) as int8 == low byte XOR 0x80
    return (v0 | (v1 << 8) | (v2 << 16) | (v3 << 24)) ^ 0x80808080;
}

// 16 outputs [o0, o0+16) for one pixel: SGPR weights (o uniform), nt store.
__device__ __forceinline__ void out_chunk(int o0,
                                          const int* __restrict__ wp_g,
                                          const float4* __restrict__ params_g,
                                          const int pk[16],
                                          int* __restrict__ ob) {
    #pragma unroll
    for (int i = 0; i < 16; ++i) {
        int o = o0 + i;                        // uniform -> s_load weights
        const int4* wv = (const int4*)(wp_g + o * 16);
        int4 w0 = wv[0], w1 = wv[1], w2 = wv[2], w3 = wv[3];
        float4 pr = params_g[o];
        int acc = __float_as_int(pr.w);        // (128-izp)*sum_w (0 here)

        acc = __builtin_amdgcn_sdot4(pk[0],  w0.x, acc, false);
        acc = __builtin_amdgcn_sdot4(pk[1],  w0.y, acc, false);
        acc = __builtin_amdgcn_sdot4(pk[2],  w0.z, acc, false);
        acc = __builtin_amdgcn_sdot4(pk[3],  w0.w, acc, false);
        acc = __builtin_amdgcn_sdot4(pk[4],  w1.x, acc, false);
        acc = __builtin_amdgcn_sdot4(pk[5],  w1.y, acc, false);
        acc = __builtin_amdgcn_sdot4(pk[6],  w1.z, acc, false);
        acc = __builtin_amdgcn_sdot4(pk[7],  w1.w, acc, false);
        acc = __builtin_amdgcn_sdot4(pk[8],  w2.x, acc, false);
        acc = __builtin_amdgcn_sdot4(pk[9],  w2.y, acc, false);
        acc = __builtin_amdgcn_sdot4(pk[10], w2.z, acc, false);
        acc = __builtin_amdgcn_sdot4(pk[11], w2.w, acc, false);
        acc = __builtin_amdgcn_sdot4(pk[12], w3.x, acc, false);
        acc = __builtin_amdgcn_sdot4(pk[13], w3.y, acc, false);
        acc = __builtin_amdgcn_sdot4(pk[14], w3.z, acc, false);
        acc = __builtin_amdgcn_sdot4(pk[15], w3.w, acc, false);

        float f = fmaf((float)acc, pr.x, pr.y);
        f = rintf(f);                          // round-half-even == jnp.round
        f = fminf(fmaxf(f, 0.0f), 255.0f);
        __builtin_nontemporal_store((int)f, ob + o * HW);
    }
}

// ---------------------------------------------------------------------------
// Main: 2048 blocks x 128 threads, 2 pixels/thread (t, t+HALF), 16 waves/CU.
// Identical to R6 EXCEPT: pixel B's 64 channel loads are issued in 4 chunks
// of 16, interleaved ahead of pixel A's 4 compute chunks — reads stay in
// flight under A's sdot4 stream instead of bursting after it (fixes the
// load/compute phase lockstep that capped HBM at 2.3 TB/s).
// ---------------------------------------------------------------------------
__global__ __launch_bounds__(128) void conv_kernel(
    const int* __restrict__ x,
    const int* __restrict__ wp_g,
    const float4* __restrict__ params_g,
    int* __restrict__ out) {

    const int t = blockIdx.x * 128 + threadIdx.x;   // pixel A id, 0..262143
    const int bA = t >> 14, pA = t & (HW - 1);
    const int tB = t + HALF;
    const int bB = tB >> 14, pB = tB & (HW - 1);

    const int* xA = x + bA * (CIN * HW) + pA;
    const int* xB = x + bB * (CIN * HW) + pB;
    int* obA = out + bA * (COUT * HW) + pA;
    int* obB = out + bB * (COUT * HW) + pB;

    // ---- pixel A: load + pack (64 coalesced dword loads) ----
    int pkA[16];
    #pragma unroll
    for (int cg = 0; cg < 16; ++cg)
        pkA[cg] = pack4(xA[(4 * cg + 0) * HW], xA[(4 * cg + 1) * HW],
                        xA[(4 * cg + 2) * HW], xA[(4 * cg + 3) * HW]);

    // ---- A compute x B prefetch, 4 interleaved chunks ----
    int pkB[16];
    #pragma unroll
    for (int c = 0; c < 4; ++c) {
        // issue B channel-groups 4c..4c+3 (16 loads, 16 raw regs)
        int raw[16];
        #pragma unroll
        for (int j = 0; j < 16; ++j)
            raw[j] = xB[(16 * c + j) * HW];

        // compute A outputs 16c..16c+15 while those loads fly (~700 cyc)
        out_chunk(16 * c, wp_g, params_g, pkA, obA);

        // consume: pack B groups 4c..4c+3
        #pragma unroll
        for (int g = 0; g < 4; ++g)
            pkB[4 * c + g] = pack4(raw[4 * g + 0], raw[4 * g + 1],
                                   raw[4 * g + 2], raw[4 * g + 3]);
    }

    // ---- pixel B: compute + store ----
    #pragma unroll
    for (int c = 0; c < 4; ++c)
        out_chunk(16 * c, wp_g, params_g, pkB, obB);
}

extern "C" void kernel_launch(void* const* d_in, const int* in_sizes, int n_in,
                              void* d_out, int out_size, void* d_ws, size_t ws_size,
                              hipStream_t stream) {
    const int*   x      = (const int*)d_in[0];     // [32,64,128,128] int32
    const float* is_p   = (const float*)d_in[1];
    const int*   izp_p  = (const int*)d_in[2];
    const int*   w      = (const int*)d_in[3];     // [64,64,1,1] int32
    const float* wscale = (const float*)d_in[4];
    const int*   wzp    = (const int*)d_in[5];
    const float* bias   = (const float*)d_in[6];
    const float* os_p   = (const float*)d_in[7];
    const int*   ozp_p  = (const int*)d_in[8];

    int* out = (int*)d_out;

    int*    wp     = (int*)d_ws;                       // 4096 B
    float4* params = (float4*)((char*)d_ws + 4096);    // 1024 B

    prep_kernel<<<1, 64, 0, stream>>>(w, wscale, wzp, bias, is_p, izp_p, os_p,
                                      ozp_p, wp, params);

    // 262144 threads x 2 px = 524288 pixels; 2048 blocks x 128 threads
    conv_kernel<<<2048, 128, 0, stream>>>(x, wp, params, out);
}

// Round 8
// 270.129 us; speedup vs baseline: 1.0500x; 1.0500x over previous
//
#include <hip/hip_runtime.h>

// Problem constants: B=32, CIN=64, COUT=64, H=W=128, 1x1 conv
#define CIN   64
#define COUT  64
#define HW    16384           // 128*128
#define NPIX  (32 * HW)       // 524288

#define TILE  64              // pixels per wave-tile (= wave width)
#define TPAD  17              // transpose tile leading dim (16 px + 1 pad)

// ---------------------------------------------------------------------------
// Prep: pack (w - wzp) into int8 dwords + fold requant params.
// wp[o*16 + k] = w[o][4k..4k+3]-wzp as 4 signed bytes (c0 in low byte).
// params[o] = { scale, bias/os + ozp, 0, as_float((128-izp)*sum_w) }
// ---------------------------------------------------------------------------
__global__ void prep_kernel(const int* __restrict__ w,
                            const float* __restrict__ wscale,
                            const int* __restrict__ wzp,
                            const float* __restrict__ bias,
                            const float* __restrict__ is_p,
                            const int* __restrict__ izp_p,
                            const float* __restrict__ os_p,
                            const int* __restrict__ ozp_p,
                            int* __restrict__ wp,
                            float4* __restrict__ params) {
    int o = threadIdx.x;
    if (o >= COUT) return;
    int zp = wzp[o];
    int sum = 0;
    #pragma unroll
    for (int k = 0; k < 16; ++k) {
        int c0 = w[o * CIN + 4 * k + 0] - zp;
        int c1 = w[o * CIN + 4 * k + 1] - zp;
        int c2 = w[o * CIN + 4 * k + 2] - zp;
        int c3 = w[o * CIN + 4 * k + 3] - zp;
        sum += c0 + c1 + c2 + c3;
        wp[o * 16 + k] = (c0 & 0xff) | ((c1 & 0xff) << 8) |
                         ((c2 & 0xff) << 16) | ((c3 & 0xff) << 24);
    }
    float4 pr;
    pr.x = is_p[0] * wscale[o] / os_p[0];
    pr.y = bias[o] / os_p[0] + (float)ozp_p[0];
    pr.z = 0.0f;
    pr.w = __int_as_float((128 - izp_p[0]) * sum);  // exact izp correction
    params[o] = pr;
}

__device__ __forceinline__ int pack4(int v0, int v1, int v2, int v3) {
    // x in [0,255]; (x-128) as int8 == low byte XOR 0x80
    return (v0 | (v1 << 8) | (v2 << 16) | (v3 << 24)) ^ 0x80808080;
}

// ---------------------------------------------------------------------------
// Lane-=-output-channel kernel. Each lane holds ITS output's 16 packed weight
// dwords + params in VGPRs for the entire kernel (weights fetched ONCE — this
// removes the per-(wave,px) 4KB weight re-broadcast that capped R3/R5/R6/R7
// at 79-110 us). A wave owns 64 pixels: lane=px loads/packs its own pixel;
// per pixel p, 16 readlane broadcasts (16 dwords — 64x less than the old
// weight broadcast) + 16 sdot4 produce all 64 outputs across lanes. Results
// are transposed through a wave-private 64x17 LDS tile (16 px at a time) into
// coalesced 64B-line nontemporal stores. No barriers anywhere.
// ---------------------------------------------------------------------------
__global__ __launch_bounds__(256, 4) void conv_kernel(
    const int* __restrict__ x,
    const int* __restrict__ wp_g,
    const float4* __restrict__ params_g,
    int* __restrict__ out) {

    __shared__ int s_t[4][COUT * TPAD];   // per-wave transpose tiles, 17.4 KB

    const int tid  = threadIdx.x;
    const int lane = tid & 63;
    const int wv   = tid >> 6;

    // ---- weights + params: once, pinned in VGPRs (lane = output o) ----
    const int4* wvp = (const int4*)(wp_g + lane * 16);
    int4 w0 = wvp[0], w1 = wvp[1], w2 = wvp[2], w3 = wvp[3];
    float4 pr = params_g[lane];
    const int accbase = __float_as_int(pr.w);   // (128-izp)*sum_w (0 here)

    // ---- this wave's 64-pixel tile ----
    const int tile = blockIdx.x * 4 + wv;       // 0..8191
    const int t0   = tile * TILE;               // global pixel base
    const int b    = t0 >> 14;                  // image (64 px never crosses)
    const int p0   = t0 & (HW - 1);

    // load + pack own pixel (lane = px): 64 coalesced dword loads
    const int* xb = x + b * (CIN * HW) + p0 + lane;
    int pk[16];
    #pragma unroll
    for (int cg = 0; cg < 16; ++cg) {
        int v0 = xb[(4 * cg + 0) * HW];
        int v1 = xb[(4 * cg + 1) * HW];
        int v2 = xb[(4 * cg + 2) * HW];
        int v3 = xb[(4 * cg + 3) * HW];
        pk[cg] = pack4(v0, v1, v2, v3);
    }

    int* ob = out + b * (COUT * HW) + p0;
    int* lds = s_t[wv];

    const int q    = lane >> 4;                 // store-phase o-group 0..3
    const int px15 = lane & 15;                 // store-phase px 0..15

    for (int s = 0; s < 4; ++s) {               // 4 sub-tiles of 16 px
        #pragma unroll
        for (int pp = 0; pp < 16; ++pp) {
            const int p = s * 16 + pp;          // wave-uniform pixel index

            // broadcast pixel p's 16 packed dwords (readlane -> SGPR)
            int acc = accbase;
            #pragma unroll
            for (int j = 0; j < 4; ++j) {
                int b0 = __builtin_amdgcn_readlane(pk[4 * j + 0], p);
                int b1 = __builtin_amdgcn_readlane(pk[4 * j + 1], p);
                int b2 = __builtin_amdgcn_readlane(pk[4 * j + 2], p);
                int b3 = __builtin_amdgcn_readlane(pk[4 * j + 3], p);
                const int4& wj = (j == 0) ? w0 : (j == 1) ? w1 : (j == 2) ? w2 : w3;
                acc = __builtin_amdgcn_sdot4(b0, wj.x, acc, false);
                acc = __builtin_amdgcn_sdot4(b1, wj.y, acc, false);
                acc = __builtin_amdgcn_sdot4(b2, wj.z, acc, false);
                acc = __builtin_amdgcn_sdot4(b3, wj.w, acc, false);
            }

            float f = fmaf((float)acc, pr.x, pr.y);   // per-lane scale/bias
            f = rintf(f);                             // round-half-even == jnp.round
            f = fminf(fmaxf(f, 0.0f), 255.0f);
            lds[lane * TPAD + pp] = (int)f;           // lane=o, col=px (2-way, free)
        }

        // transpose sub-tile out: 16 instrs, each 4 o-groups x 16 px = 4 full
        // 64B lines; compiler inserts the lgkmcnt wait (wave-private region)
        #pragma unroll
        for (int i = 0; i < 16; ++i) {
            int oo = q + 4 * i;
            int v = lds[oo * TPAD + px15];
            __builtin_nontemporal_store(v, ob + oo * HW + s * 16 + px15);
        }
    }
}

extern "C" void kernel_launch(void* const* d_in, const int* in_sizes, int n_in,
                              void* d_out, int out_size, void* d_ws, size_t ws_size,
                              hipStream_t stream) {
    const int*   x      = (const int*)d_in[0];     // [32,64,128,128] int32
    const float* is_p   = (const float*)d_in[1];
    const int*   izp_p  = (const int*)d_in[2];
    const int*   w      = (const int*)d_in[3];     // [64,64,1,1] int32
    const float* wscale = (const float*)d_in[4];
    const int*   wzp    = (const int*)d_in[5];
    const float* bias   = (const float*)d_in[6];
    const float* os_p   = (const float*)d_in[7];
    const int*   ozp_p  = (const int*)d_in[8];

    int* out = (int*)d_out;

    int*    wp     = (int*)d_ws;                       // 4096 B
    float4* params = (float4*)((char*)d_ws + 4096);    // 1024 B

    prep_kernel<<<1, 64, 0, stream>>>(w, wscale, wzp, bias, is_p, izp_p, os_p,
                                      ozp_p, wp, params);

    // 8192 wave-tiles x 64 px = 524288 pixels; 2048 blocks x 4 waves
    conv_kernel<<<2048, 256, 0, stream>>>(x, wp, params, out);
}